// Round 1
// baseline (425.410 us; speedup 1.0000x reference)
//
#include <hip/hip_runtime.h>
#include <hip/hip_bf16.h>

// EdgePredict: out = softmax((h[u] * h[v]) @ W1 @ W2 @ W3 + bias-chain)
// Key insight: the MLP chain is purely linear (no activations), so collapse
// W1@W2@W3 -> Wc [256,2] and fold biases -> bf [2]. Per edge this reduces
// 82 KFLOP to ~1.5 KFLOP; the kernel becomes a gather-bandwidth problem.

#define D 256

// ---------------------------------------------------------------------------
// Kernel 1: collapse weights. One block, 256 threads.
// ws layout (floats): [0..255] Wc[:,0], [256..511] Wc[:,1], [512] bf0, [513] bf1
// ---------------------------------------------------------------------------
__global__ __launch_bounds__(256) void collapse_weights(
    const float* __restrict__ W1, const float* __restrict__ b1,
    const float* __restrict__ W2, const float* __restrict__ b2,
    const float* __restrict__ W3, const float* __restrict__ b3,
    float* __restrict__ wc)
{
    __shared__ float T[128][2];  // T = W2 @ W3  (128x64 @ 64x2)
    const int t = threadIdx.x;   // 0..255

    {
        const int j = t >> 1, c = t & 1;
        float s = 0.f;
        #pragma unroll 8
        for (int k = 0; k < 64; ++k) s += W2[j * 64 + k] * W3[k * 2 + c];
        T[j][c] = s;
    }
    __syncthreads();

    // Wc[d][c] = sum_j W1[d][j] * T[j][c]
    float s0 = 0.f, s1 = 0.f;
    #pragma unroll 8
    for (int j = 0; j < 128; ++j) {
        const float w = W1[t * 128 + j];
        s0 += w * T[j][0];
        s1 += w * T[j][1];
    }
    wc[t]       = s0;
    wc[256 + t] = s1;

    if (t == 0) {
        // bias chain: b1@W2@W3 + b2@W3 + b3  (b1,b2 are zeros in setup, but
        // compute anyway for generality)
        float f0 = b3[0], f1 = b3[1];
        for (int j = 0; j < 128; ++j) { f0 += b1[j] * T[j][0]; f1 += b1[j] * T[j][1]; }
        for (int k = 0; k < 64; ++k)  { f0 += b2[k] * W3[k * 2 + 0]; f1 += b2[k] * W3[k * 2 + 1]; }
        wc[512] = f0;
        wc[513] = f1;
    }
}

// ---------------------------------------------------------------------------
// Kernel 2: one wave (64 lanes) per edge, grid-stride over edges.
// Lane i covers dims [4i, 4i+4): coalesced float4 loads of both rows.
// ---------------------------------------------------------------------------
__global__ __launch_bounds__(256) void edge_predict(
    const float* __restrict__ h, const int2* __restrict__ edges,
    const float* __restrict__ wc, float2* __restrict__ out, int E)
{
    const int lane = threadIdx.x & 63;
    const int wid  = blockIdx.x * (blockDim.x >> 6) + (threadIdx.x >> 6);
    const int nw   = gridDim.x * (blockDim.x >> 6);

    // Loop-invariant: collapsed weight columns + folded bias (one load per wave)
    const float4 w0 = ((const float4*)wc)[lane];
    const float4 w1 = ((const float4*)(wc + 256))[lane];
    const float bf0 = wc[512];
    const float bf1 = wc[513];

    for (int e = wid; e < E; e += nw) {
        const int2 ed = edges[e];  // same addr across wave -> broadcast
        const float4* __restrict__ ru = (const float4*)(h + (size_t)ed.x * D);
        const float4* __restrict__ rv = (const float4*)(h + (size_t)ed.y * D);
        const float4 a = ru[lane];
        const float4 b = rv[lane];

        const float px = a.x * b.x, py = a.y * b.y, pz = a.z * b.z, pw = a.w * b.w;
        float s0 = px * w0.x + py * w0.y + pz * w0.z + pw * w0.w;
        float s1 = px * w1.x + py * w1.y + pz * w1.z + pw * w1.w;

        // 64-lane butterfly reduction of (s0, s1)
        #pragma unroll
        for (int m = 32; m > 0; m >>= 1) {
            s0 += __shfl_xor(s0, m, 64);
            s1 += __shfl_xor(s1, m, 64);
        }

        if (lane == 0) {
            const float o0 = s0 + bf0, o1 = s1 + bf1;
            const float mx = fmaxf(o0, o1);
            const float e0 = __expf(o0 - mx), e1 = __expf(o1 - mx);
            const float r  = 1.0f / (e0 + e1);
            out[e] = make_float2(e0 * r, e1 * r);
        }
    }
}

// ---------------------------------------------------------------------------
extern "C" void kernel_launch(void* const* d_in, const int* in_sizes, int n_in,
                              void* d_out, int out_size, void* d_ws, size_t ws_size,
                              hipStream_t stream)
{
    const float* h     = (const float*)d_in[0];
    const int2*  edges = (const int2*)d_in[1];   // harness converts int64 -> int32
    const float* W1    = (const float*)d_in[2];
    const float* b1    = (const float*)d_in[3];
    const float* W2    = (const float*)d_in[4];
    const float* b2    = (const float*)d_in[5];
    const float* W3    = (const float*)d_in[6];
    const float* b3    = (const float*)d_in[7];

    float* wc = (float*)d_ws;                    // 514 floats
    float2* out = (float2*)d_out;

    const int E = in_sizes[1] / 2;

    collapse_weights<<<1, 256, 0, stream>>>(W1, b1, W2, b2, W3, b3, wc);

    // 2048 blocks x 4 waves = 8192 waves (full residency), ~122 edges/wave
    edge_predict<<<2048, 256, 0, stream>>>(h, edges, wc, out, E);
}

// Round 2
// 328.443 us; speedup vs baseline: 1.2952x; 1.2952x over previous
//
#include <hip/hip_runtime.h>
#include <hip/hip_bf16.h>

// EdgePredict: out = softmax((h[u]*h[v]) @ W1 @ W2 @ W3 + biases)
// R0 insight: MLP chain is linear -> collapse to Wc[256,2] + bias[2].
// R1 insight: 2-class softmax = sigmoid(logit1 - logit0) -> only the
//   difference column wd = Wc[:,1]-Wc[:,0] is needed (6 shuffles, not 12).
// R2 move: gather is fabric-BW bound (977 MB beyond-L2 @3.5 TB/s). Convert h
//   to a packed bf16 table in d_ws once per call -> gather bytes halve.

#define D 256

// ---------------------------------------------------------------------------
// ws layout: [0..255] wd (float), [256] bd, table (bf16 packed) at +512 floats
// ---------------------------------------------------------------------------
__global__ __launch_bounds__(256) void collapse_weights(
    const float* __restrict__ W1, const float* __restrict__ b1,
    const float* __restrict__ W2, const float* __restrict__ b2,
    const float* __restrict__ W3, const float* __restrict__ b3,
    float* __restrict__ wc)
{
    __shared__ float T[128][2];  // T = W2 @ W3  (128x64 @ 64x2)
    const int t = threadIdx.x;   // 0..255

    {
        const int j = t >> 1, c = t & 1;
        float s = 0.f;
        #pragma unroll 8
        for (int k = 0; k < 64; ++k) s += W2[j * 64 + k] * W3[k * 2 + c];
        T[j][c] = s;
    }
    __syncthreads();

    float s0 = 0.f, s1 = 0.f;
    #pragma unroll 8
    for (int j = 0; j < 128; ++j) {
        const float w = W1[t * 128 + j];
        s0 += w * T[j][0];
        s1 += w * T[j][1];
    }
    wc[t] = s1 - s0;  // wd[t]

    if (t == 0) {
        float f0 = b3[0], f1 = b3[1];
        for (int j = 0; j < 128; ++j) { f0 += b1[j] * T[j][0]; f1 += b1[j] * T[j][1]; }
        for (int k = 0; k < 64; ++k)  { f0 += b2[k] * W3[k * 2 + 0]; f1 += b2[k] * W3[k * 2 + 1]; }
        wc[256] = f1 - f0;  // bd
    }
}

// ---------------------------------------------------------------------------
// fp32 h -> packed bf16 table (round-to-nearest-even)
// ---------------------------------------------------------------------------
__device__ __forceinline__ unsigned bf16rn(float f) {
    unsigned u = __float_as_uint(f);
    u += 0x7fffu + ((u >> 16) & 1u);
    return u >> 16;
}

__global__ __launch_bounds__(256) void to_bf16(
    const float4* __restrict__ h, uint2* __restrict__ hb, int nvec)
{
    int i = blockIdx.x * blockDim.x + threadIdx.x;
    const int stride = gridDim.x * blockDim.x;
    for (; i < nvec; i += stride) {
        const float4 f = h[i];
        uint2 o;
        o.x = bf16rn(f.x) | (bf16rn(f.y) << 16);
        o.y = bf16rn(f.z) | (bf16rn(f.w) << 16);
        hb[i] = o;
    }
}

// ---------------------------------------------------------------------------
// One wave per edge, bf16 gather (512 B/row), delta-logit + sigmoid.
// ---------------------------------------------------------------------------
__device__ __forceinline__ float blo(unsigned u) { return __uint_as_float(u << 16); }
__device__ __forceinline__ float bhi(unsigned u) { return __uint_as_float(u & 0xffff0000u); }

__global__ __launch_bounds__(256) void edge_predict_bf16(
    const uint2* __restrict__ hb, const int2* __restrict__ edges,
    const float* __restrict__ wc, float2* __restrict__ out, int E)
{
    const int lane = threadIdx.x & 63;
    const int wid  = blockIdx.x * (blockDim.x >> 6) + (threadIdx.x >> 6);
    const int nw   = gridDim.x * (blockDim.x >> 6);

    const float4 wd = ((const float4*)wc)[lane];  // dims [4l..4l+3]
    const float  bd = wc[256];

    for (int e = wid; e < E; e += 2 * nw) {
        const int e2 = e + nw;
        const int2 ed1 = edges[e];
        const uint2 ua1 = hb[(size_t)ed1.x * 64 + lane];
        const uint2 ub1 = hb[(size_t)ed1.y * 64 + lane];
        int2 ed2; uint2 ua2, ub2;
        if (e2 < E) {
            ed2 = edges[e2];
            ua2 = hb[(size_t)ed2.x * 64 + lane];
            ub2 = hb[(size_t)ed2.y * 64 + lane];
        }

        float d1 = blo(ua1.x) * blo(ub1.x) * wd.x
                 + bhi(ua1.x) * bhi(ub1.x) * wd.y
                 + blo(ua1.y) * blo(ub1.y) * wd.z
                 + bhi(ua1.y) * bhi(ub1.y) * wd.w;
        #pragma unroll
        for (int m = 32; m > 0; m >>= 1) d1 += __shfl_xor(d1, m, 64);
        if (lane == 0) {
            const float p1 = 1.0f / (1.0f + __expf(-(d1 + bd)));
            out[e] = make_float2(1.0f - p1, p1);
        }

        if (e2 < E) {
            float d2 = blo(ua2.x) * blo(ub2.x) * wd.x
                     + bhi(ua2.x) * bhi(ub2.x) * wd.y
                     + blo(ua2.y) * blo(ub2.y) * wd.z
                     + bhi(ua2.y) * bhi(ub2.y) * wd.w;
            #pragma unroll
            for (int m = 32; m > 0; m >>= 1) d2 += __shfl_xor(d2, m, 64);
            if (lane == 0) {
                const float p1 = 1.0f / (1.0f + __expf(-(d2 + bd)));
                out[e2] = make_float2(1.0f - p1, p1);
            }
        }
    }
}

// ---------------------------------------------------------------------------
// Fallback: fp32 gather (used only if ws too small for the bf16 table)
// ---------------------------------------------------------------------------
__global__ __launch_bounds__(256) void edge_predict_f32(
    const float* __restrict__ h, const int2* __restrict__ edges,
    const float* __restrict__ wc, float2* __restrict__ out, int E)
{
    const int lane = threadIdx.x & 63;
    const int wid  = blockIdx.x * (blockDim.x >> 6) + (threadIdx.x >> 6);
    const int nw   = gridDim.x * (blockDim.x >> 6);

    const float4 wd = ((const float4*)wc)[lane];
    const float  bd = wc[256];

    for (int e = wid; e < E; e += nw) {
        const int2 ed = edges[e];
        const float4 a = ((const float4*)(h + (size_t)ed.x * D))[lane];
        const float4 b = ((const float4*)(h + (size_t)ed.y * D))[lane];
        float d = a.x * b.x * wd.x + a.y * b.y * wd.y
                + a.z * b.z * wd.z + a.w * b.w * wd.w;
        #pragma unroll
        for (int m = 32; m > 0; m >>= 1) d += __shfl_xor(d, m, 64);
        if (lane == 0) {
            const float p1 = 1.0f / (1.0f + __expf(-(d + bd)));
            out[e] = make_float2(1.0f - p1, p1);
        }
    }
}

// ---------------------------------------------------------------------------
extern "C" void kernel_launch(void* const* d_in, const int* in_sizes, int n_in,
                              void* d_out, int out_size, void* d_ws, size_t ws_size,
                              hipStream_t stream)
{
    const float* h     = (const float*)d_in[0];
    const int2*  edges = (const int2*)d_in[1];
    const float* W1    = (const float*)d_in[2];
    const float* b1    = (const float*)d_in[3];
    const float* W2    = (const float*)d_in[4];
    const float* b2    = (const float*)d_in[5];
    const float* W3    = (const float*)d_in[6];
    const float* b3    = (const float*)d_in[7];

    float*  wc  = (float*)d_ws;
    float2* out = (float2*)d_out;

    const int nNodes = in_sizes[0] / D;
    const int E      = in_sizes[1] / 2;
    const size_t tbl_off   = 512 * sizeof(float);            // 2 KB, keeps 16B align
    const size_t tbl_bytes = (size_t)nNodes * D * 2;         // bf16 table

    collapse_weights<<<1, 256, 0, stream>>>(W1, b1, W2, b2, W3, b3, wc);

    if (ws_size >= tbl_off + tbl_bytes) {
        uint2* hb = (uint2*)((char*)d_ws + tbl_off);
        const int nvec = nNodes * (D / 4);                   // float4 groups
        to_bf16<<<4096, 256, 0, stream>>>((const float4*)h, hb, nvec);
        edge_predict_bf16<<<2048, 256, 0, stream>>>(hb, edges, wc, out, E);
    } else {
        edge_predict_f32<<<2048, 256, 0, stream>>>(h, edges, wc, out, E);
    }
}